// Round 2
// baseline (586.575 us; speedup 1.0000x reference)
//
#include <hip/hip_runtime.h>

// Shapes fixed by setup_inputs(): b=8, s=4096, h=16, p=64, n=64, L=64.
// Reduction: out[b,h,p,n] = sum_t exp(Total(b,h) - P(b,h,t)) * X[b,t,h,p] * B[b,t,h,n]
// where P = inclusive prefix-sum of A over t, Total = P[s-1]. (Chunked scan telescopes.)

constexpr int Bn = 8;
constexpr int S  = 4096;
constexpr int H  = 16;
constexpr int P  = 64;
constexpr int N  = 64;

constexpr int NCH = 8;         // t-chunks per (b,h) pair -> 1024 blocks = 4/CU exactly
constexpr int TCH = S / NCH;   // 512 timesteps per chunk
constexpr int TB  = 32;        // timesteps staged per LDS buffer
constexpr int NIT = TCH / TB;  // 16 buffer iterations per block

typedef unsigned int u32;

// async global->LDS, 16B per lane. LDS dest is wave-uniform base + lane*16.
__device__ __forceinline__ void gll16(const float* g, void* l) {
  __builtin_amdgcn_global_load_lds(
      (const __attribute__((address_space(1))) u32*)g,
      (__attribute__((address_space(3))) u32*)l, 16, 0, 0);
}
__device__ __forceinline__ void gll4(const float* g, void* l) {
  __builtin_amdgcn_global_load_lds(
      (const __attribute__((address_space(1))) u32*)g,
      (__attribute__((address_space(3))) u32*)l, 4, 0, 0);
}

// ---------------- Kernel 1: per-(b,h) prefix scan of A -> weights ----------------
__global__ __launch_bounds__(256) void scan_weights(
    const float* __restrict__ A, float* __restrict__ W) {
  const int pair = blockIdx.x;         // 0..Bn*H-1
  const int bb = pair / H, hh = pair % H;
  const int tid = threadIdx.x;
  constexpr int TPT = S / 256;         // 16 elements per thread

  float vals[TPT];
  float local = 0.f;
  const int t0 = tid * TPT;
  #pragma unroll
  for (int i = 0; i < TPT; ++i) {
    float a = A[((size_t)bb * S + t0 + i) * H + hh];
    local += a;
    vals[i] = local;                   // inclusive within thread
  }

  __shared__ float sums[256];
  sums[tid] = local;
  __syncthreads();
  for (int off = 1; off < 256; off <<= 1) {
    float v = sums[tid];
    float add = (tid >= off) ? sums[tid - off] : 0.f;
    __syncthreads();
    sums[tid] = v + add;
    __syncthreads();
  }
  const float total = sums[255];
  const float excl  = sums[tid] - local;

  float* Wp = W + (size_t)pair * S;
  #pragma unroll
  for (int i = 0; i < TPT; ++i) {
    Wp[t0 + i] = __expf(total - (excl + vals[i]));  // exponent <= 0 (A <= 0)
  }
}

// ---------------- Kernel 2: weighted outer-product accumulation ----------------
// One block per (pair, chunk). 256 threads = 4 waves. Each lane owns an 8x8 tile
// of the 64x64 output; the 4 waves split the staged timesteps (wave w -> rows
// w*8..w*8+7 of each 32-row buffer) and combine partials via an LDS tree.
// Staging is pure global_load_lds (no VGPR round-trip, no staging registers).
// LDS buffer layout (float4 units): [0..511]=X rows [32][16], [512..1023]=B rows,
// [1024..1039]=W (64 floats, first 32 valid). Double-buffered: 2*16.64 KB.
__global__ __launch_bounds__(256, 4) void outer_accum(
    const float* __restrict__ X, const float* __restrict__ Bm,
    const float* __restrict__ W, float* __restrict__ out) {
  __shared__ float4 smem[2][1040];     // 33,280 B total -> 4 blocks/CU

  const int bid  = blockIdx.x;
  const int pair = bid / NCH;
  const int ch   = bid % NCH;
  const int tid  = threadIdx.x;
  const int lane = tid & 63;
  const int wid  = tid >> 6;           // wave id 0..3
  const int t_begin = ch * TCH;

  // compute mapping: lane covers an 8x8 tile of the 64x64 (p,n) output
  const int pr = (lane >> 3) * 8;      // p base
  const int nc = (lane & 7) * 8;       // n base

  const int bb = pair / H, hh = pair % H;
  constexpr int HP = H * P;            // 1024 floats: X row stride over t
  constexpr int HN = H * N;            // 1024 floats: B row stride over t

  // staging: wave w fills buffer rows w*8 .. w*8+7 (two 64-float4 issues of 4 rows)
  const int r0 = wid * 8 + (lane >> 4);      // staged row for issue 0 (issue 1: +4)
  const int c0 = (lane & 15) * 4;            // float column
  const float* gx = X  + (size_t)bb * S * HP + (size_t)hh * P + (size_t)r0 * HP + c0;
  const float* gb = Bm + (size_t)bb * S * HN + (size_t)hh * N + (size_t)r0 * HN + c0;
  const float* Wp = W + (size_t)pair * S;
  const float* gw = Wp + (lane & 31);        // lanes 32..63 write harmless duplicates

  float acc[8][8];
  #pragma unroll
  for (int i = 0; i < 8; ++i)
    #pragma unroll
    for (int k = 0; k < 8; ++k) acc[i][k] = 0.f;

  auto STAGE = [&](int buf, int t0) {
    float4* Xs = &smem[buf][0];
    float4* Bs = &smem[buf][512];
    float*  Ws = (float*)&smem[buf][1024];
    const float* px = gx + (size_t)t0 * HP;
    const float* pb = gb + (size_t)t0 * HN;
    gll16(px,            Xs + wid * 128);        // rows w*8 .. +3
    gll16(px + 4 * HP,   Xs + wid * 128 + 64);   // rows w*8+4 .. +7
    gll16(pb,            Bs + wid * 128);
    gll16(pb + 4 * HN,   Bs + wid * 128 + 64);
    if (wid == 0) gll4(gw + t0, Ws);             // 32 decay weights (+32 dup)
  };

  STAGE(0, t_begin);
  __syncthreads();                               // drains vmcnt -> buf0 ready

  for (int it = 0; it < NIT; ++it) {
    const int cur = it & 1;
    if (it + 1 < NIT) STAGE(cur ^ 1, t_begin + (it + 1) * TB);  // async prefetch

    const float* Xs = (const float*)&smem[cur][0];
    const float* Bs = (const float*)&smem[cur][512];
    const float* Ws = (const float*)&smem[cur][1024];
    #pragma unroll
    for (int j = 0; j < 8; ++j) {
      const int tt = wid * 8 + j;                // this wave's timestep in buffer
      const float w = Ws[tt];                    // broadcast read
      const float4 xa = *(const float4*)(Xs + tt * 64 + pr);
      const float4 xb = *(const float4*)(Xs + tt * 64 + pr + 4);
      const float4 ba = *(const float4*)(Bs + tt * 64 + nc);
      const float4 bc = *(const float4*)(Bs + tt * 64 + nc + 4);
      const float xs[8] = {xa.x * w, xa.y * w, xa.z * w, xa.w * w,
                           xb.x * w, xb.y * w, xb.z * w, xb.w * w};
      const float bs[8] = {ba.x, ba.y, ba.z, ba.w, bc.x, bc.y, bc.z, bc.w};
      #pragma unroll
      for (int i = 0; i < 8; ++i)
        #pragma unroll
        for (int k = 0; k < 8; ++k)
          acc[i][k] = fmaf(xs[i], bs[k], acc[i][k]);
    }
    __syncthreads();   // drains prefetch; also guards buffer reuse
  }

  // ---- cross-wave reduction of the 4 t-phase partials (LDS tree) ----
  float* red = (float*)&smem[0][0];    // 2 regions of 64*64 floats (16 KB each)

  auto publish = [&](int reg) {
    float4* r = (float4*)(red + reg * 4096);
    #pragma unroll
    for (int i = 0; i < 8; ++i) {
      r[((pr + i) * 64 + nc) / 4]     = make_float4(acc[i][0], acc[i][1], acc[i][2], acc[i][3]);
      r[((pr + i) * 64 + nc) / 4 + 1] = make_float4(acc[i][4], acc[i][5], acc[i][6], acc[i][7]);
    }
  };
  auto absorb = [&](int reg) {
    const float4* r = (const float4*)(red + reg * 4096);
    #pragma unroll
    for (int i = 0; i < 8; ++i) {
      const float4 v0 = r[((pr + i) * 64 + nc) / 4];
      const float4 v1 = r[((pr + i) * 64 + nc) / 4 + 1];
      acc[i][0] += v0.x; acc[i][1] += v0.y; acc[i][2] += v0.z; acc[i][3] += v0.w;
      acc[i][4] += v1.x; acc[i][5] += v1.y; acc[i][6] += v1.z; acc[i][7] += v1.w;
    }
  };

  if (wid == 1) publish(0);
  if (wid == 3) publish(1);
  __syncthreads();
  if (wid == 0) absorb(0);
  if (wid == 2) absorb(1);
  __syncthreads();
  if (wid == 2) publish(0);
  __syncthreads();
  if (wid == 0) {
    absorb(0);
    float* outp = out + (size_t)pair * P * N;  // out[b,h,p,n]
    #pragma unroll
    for (int i = 0; i < 8; ++i)
      #pragma unroll
      for (int k = 0; k < 8; ++k)
        atomicAdd(&outp[(size_t)(pr + i) * N + (nc + k)], acc[i][k]);
  }
}

extern "C" void kernel_launch(void* const* d_in, const int* in_sizes, int n_in,
                              void* d_out, int out_size, void* d_ws, size_t ws_size,
                              hipStream_t stream) {
  const float* X = (const float*)d_in[0];   // (b, s, h, p)
  const float* A = (const float*)d_in[1];   // (b, s, h)
  const float* B = (const float*)d_in[2];   // (b, s, h, n)
  float* out = (float*)d_out;               // (b, h, p, n)
  float* W   = (float*)d_ws;                // Bn*H*S floats = 2 MB scratch

  // out is poisoned 0xAA before every launch; atomics need zeros
  hipMemsetAsync(d_out, 0, (size_t)out_size * sizeof(float), stream);

  scan_weights<<<Bn * H, 256, 0, stream>>>(A, W);
  outer_accum<<<Bn * H * NCH, 256, 0, stream>>>(X, B, W, out);
}

// Round 3
// 584.011 us; speedup vs baseline: 1.0044x; 1.0044x over previous
//
#include <hip/hip_runtime.h>

// Shapes fixed by setup_inputs(): b=8, s=4096, h=16, p=64, n=64, L=64.
// Reduction: out[b,h,p,n] = sum_t exp(Total(b,h) - P(b,h,t)) * X[b,t,h,p] * B[b,t,h,n]
// where P = inclusive prefix-sum of A over t, Total = P[s-1]. (Chunked scan telescopes.)

constexpr int Bn = 8;
constexpr int S  = 4096;
constexpr int H  = 16;
constexpr int P  = 64;
constexpr int N  = 64;

constexpr int NCH = 8;         // t-chunks per (b,h) pair -> 1024 blocks = 4/CU exactly
constexpr int TCH = S / NCH;   // 512 timesteps per chunk
constexpr int TB  = 32;        // timesteps staged per LDS buffer
constexpr int NIT = TCH / TB;  // 16 buffer iterations per block

typedef unsigned int u32;

// async global->LDS, 16B per lane. LDS dest is wave-uniform base + lane*16.
__device__ __forceinline__ void gll16(const float* g, void* l) {
  __builtin_amdgcn_global_load_lds(
      (const __attribute__((address_space(1))) u32*)g,
      (__attribute__((address_space(3))) u32*)l, 16, 0, 0);
}
__device__ __forceinline__ void gll4(const float* g, void* l) {
  __builtin_amdgcn_global_load_lds(
      (const __attribute__((address_space(1))) u32*)g,
      (__attribute__((address_space(3))) u32*)l, 4, 0, 0);
}

// ---------------- Kernel 1: per-(b,h) prefix scan of A -> weights ----------------
__global__ __launch_bounds__(256) void scan_weights(
    const float* __restrict__ A, float* __restrict__ W) {
  const int pair = blockIdx.x;         // 0..Bn*H-1
  const int bb = pair / H, hh = pair % H;
  const int tid = threadIdx.x;
  constexpr int TPT = S / 256;         // 16 elements per thread

  float vals[TPT];
  float local = 0.f;
  const int t0 = tid * TPT;
  #pragma unroll
  for (int i = 0; i < TPT; ++i) {
    float a = A[((size_t)bb * S + t0 + i) * H + hh];
    local += a;
    vals[i] = local;                   // inclusive within thread
  }

  __shared__ float sums[256];
  sums[tid] = local;
  __syncthreads();
  for (int off = 1; off < 256; off <<= 1) {
    float v = sums[tid];
    float add = (tid >= off) ? sums[tid - off] : 0.f;
    __syncthreads();
    sums[tid] = v + add;
    __syncthreads();
  }
  const float total = sums[255];
  const float excl  = sums[tid] - local;

  float* Wp = W + (size_t)pair * S;
  #pragma unroll
  for (int i = 0; i < TPT; ++i) {
    Wp[t0 + i] = __expf(total - (excl + vals[i]));  // exponent <= 0 (A <= 0)
  }
}

// ---------------- Kernel 2: weighted outer-product accumulation ----------------
// One block per (pair, chunk). 256 threads = 4 waves. Each lane owns an 8x8 tile
// of the 64x64 output; the 4 waves split the staged timesteps (wave w -> rows
// w*8..w*8+7 of each 32-row buffer) and combine partials via an LDS tree.
// Staging is pure global_load_lds (no VGPR round-trip, no staging registers).
// LDS buffer layout (float4 units): [0..511]=X rows [32][16], [512..1023]=B rows,
// [1024..1039]=W (64 floats, first 32 valid). Double-buffered: 2*16.64 KB.
//
// waves_per_eu pinned to exactly 4 (16 waves/CU = 4 blocks/CU, matching the LDS
// limit): with a min-only bound of 4 the allocator chased the 8-waves/EU 64-VGPR
// bucket and spilled acc[8][8] to scratch (rounds 1-2: VGPR=64, +1.1 GB HBM
// scratch traffic). Exact range gives the 128-VGPR budget this kernel needs.
__global__ __launch_bounds__(256)
__attribute__((amdgpu_waves_per_eu(4, 4)))
void outer_accum(
    const float* __restrict__ X, const float* __restrict__ Bm,
    const float* __restrict__ W, float* __restrict__ out) {
  __shared__ float4 smem[2][1040];     // 33,280 B total -> 4 blocks/CU

  const int bid  = blockIdx.x;
  const int pair = bid / NCH;
  const int ch   = bid % NCH;
  const int tid  = threadIdx.x;
  const int lane = tid & 63;
  const int wid  = tid >> 6;           // wave id 0..3
  const int t_begin = ch * TCH;

  // compute mapping: lane covers an 8x8 tile of the 64x64 (p,n) output
  const int pr = (lane >> 3) * 8;      // p base
  const int nc = (lane & 7) * 8;       // n base

  const int bb = pair / H, hh = pair % H;
  constexpr int HP = H * P;            // 1024 floats: X row stride over t
  constexpr int HN = H * N;            // 1024 floats: B row stride over t

  // staging: wave w fills buffer rows w*8 .. w*8+7 (two 64-float4 issues of 4 rows)
  const int r0 = wid * 8 + (lane >> 4);      // staged row for issue 0 (issue 1: +4)
  const int c0 = (lane & 15) * 4;            // float column
  const float* gx = X  + (size_t)bb * S * HP + (size_t)hh * P + (size_t)r0 * HP + c0;
  const float* gb = Bm + (size_t)bb * S * HN + (size_t)hh * N + (size_t)r0 * HN + c0;
  const float* Wp = W + (size_t)pair * S;
  const float* gw = Wp + (lane & 31);        // lanes 32..63 write harmless duplicates

  float acc[8][8];
  #pragma unroll
  for (int i = 0; i < 8; ++i)
    #pragma unroll
    for (int k = 0; k < 8; ++k) acc[i][k] = 0.f;

  auto STAGE = [&](int buf, int t0) {
    float4* Xs = &smem[buf][0];
    float4* Bs = &smem[buf][512];
    float*  Ws = (float*)&smem[buf][1024];
    const float* px = gx + (size_t)t0 * HP;
    const float* pb = gb + (size_t)t0 * HN;
    gll16(px,            Xs + wid * 128);        // rows w*8 .. +3
    gll16(px + 4 * HP,   Xs + wid * 128 + 64);   // rows w*8+4 .. +7
    gll16(pb,            Bs + wid * 128);
    gll16(pb + 4 * HN,   Bs + wid * 128 + 64);
    if (wid == 0) gll4(gw + t0, Ws);             // 32 decay weights (+32 dup)
  };

  STAGE(0, t_begin);
  __syncthreads();                               // drains vmcnt -> buf0 ready

  for (int it = 0; it < NIT; ++it) {
    const int cur = it & 1;
    if (it + 1 < NIT) STAGE(cur ^ 1, t_begin + (it + 1) * TB);  // async prefetch

    const float* Xs = (const float*)&smem[cur][0];
    const float* Bs = (const float*)&smem[cur][512];
    const float* Ws = (const float*)&smem[cur][1024];
    #pragma unroll
    for (int j = 0; j < 8; ++j) {
      const int tt = wid * 8 + j;                // this wave's timestep in buffer
      const float w = Ws[tt];                    // broadcast read
      const float4 xa = *(const float4*)(Xs + tt * 64 + pr);
      const float4 xb = *(const float4*)(Xs + tt * 64 + pr + 4);
      const float4 ba = *(const float4*)(Bs + tt * 64 + nc);
      const float4 bc = *(const float4*)(Bs + tt * 64 + nc + 4);
      const float xs[8] = {xa.x * w, xa.y * w, xa.z * w, xa.w * w,
                           xb.x * w, xb.y * w, xb.z * w, xb.w * w};
      const float bs[8] = {ba.x, ba.y, ba.z, ba.w, bc.x, bc.y, bc.z, bc.w};
      #pragma unroll
      for (int i = 0; i < 8; ++i)
        #pragma unroll
        for (int k = 0; k < 8; ++k)
          acc[i][k] = fmaf(xs[i], bs[k], acc[i][k]);
    }
    __syncthreads();   // drains prefetch; also guards buffer reuse
  }

  // ---- cross-wave reduction of the 4 t-phase partials (LDS tree) ----
  float* red = (float*)&smem[0][0];    // 2 regions of 64*64 floats (16 KB each)

  auto publish = [&](int reg) {
    float4* r = (float4*)(red + reg * 4096);
    #pragma unroll
    for (int i = 0; i < 8; ++i) {
      r[((pr + i) * 64 + nc) / 4]     = make_float4(acc[i][0], acc[i][1], acc[i][2], acc[i][3]);
      r[((pr + i) * 64 + nc) / 4 + 1] = make_float4(acc[i][4], acc[i][5], acc[i][6], acc[i][7]);
    }
  };
  auto absorb = [&](int reg) {
    const float4* r = (const float4*)(red + reg * 4096);
    #pragma unroll
    for (int i = 0; i < 8; ++i) {
      const float4 v0 = r[((pr + i) * 64 + nc) / 4];
      const float4 v1 = r[((pr + i) * 64 + nc) / 4 + 1];
      acc[i][0] += v0.x; acc[i][1] += v0.y; acc[i][2] += v0.z; acc[i][3] += v0.w;
      acc[i][4] += v1.x; acc[i][5] += v1.y; acc[i][6] += v1.z; acc[i][7] += v1.w;
    }
  };

  if (wid == 1) publish(0);
  if (wid == 3) publish(1);
  __syncthreads();
  if (wid == 0) absorb(0);
  if (wid == 2) absorb(1);
  __syncthreads();
  if (wid == 2) publish(0);
  __syncthreads();
  if (wid == 0) {
    absorb(0);
    float* outp = out + (size_t)pair * P * N;  // out[b,h,p,n]
    #pragma unroll
    for (int i = 0; i < 8; ++i)
      #pragma unroll
      for (int k = 0; k < 8; ++k)
        atomicAdd(&outp[(size_t)(pr + i) * N + (nc + k)], acc[i][k]);
  }
}

extern "C" void kernel_launch(void* const* d_in, const int* in_sizes, int n_in,
                              void* d_out, int out_size, void* d_ws, size_t ws_size,
                              hipStream_t stream) {
  const float* X = (const float*)d_in[0];   // (b, s, h, p)
  const float* A = (const float*)d_in[1];   // (b, s, h)
  const float* B = (const float*)d_in[2];   // (b, s, h, n)
  float* out = (float*)d_out;               // (b, h, p, n)
  float* W   = (float*)d_ws;                // Bn*H*S floats = 2 MB scratch

  // out is poisoned 0xAA before every launch; atomics need zeros
  hipMemsetAsync(d_out, 0, (size_t)out_size * sizeof(float), stream);

  scan_weights<<<Bn * H, 256, 0, stream>>>(A, W);
  outer_accum<<<Bn * H * NCH, 256, 0, stream>>>(X, B, W, out);
}